// Round 3
// baseline (262.831 us; speedup 1.0000x reference)
//
#include <hip/hip_runtime.h>
#include <math.h>

#define HWSZ 6400
#define WIMG 80
#define HIMG 80
#define BEPS 1e-5f

typedef __attribute__((ext_vector_type(8))) short short8;
typedef __attribute__((ext_vector_type(4))) float f32x4;
typedef __attribute__((ext_vector_type(4))) unsigned u32x4;

__device__ __forceinline__ unsigned short f2b(float f) {
    unsigned u = __builtin_bit_cast(unsigned, f);
    u += 0x7fffu + ((u >> 16) & 1u);
    return (unsigned short)(u >> 16);
}
__device__ __forceinline__ float b2f(unsigned short h) {
    unsigned u = ((unsigned)h) << 16;
    return __builtin_bit_cast(float, u);
}
__device__ __forceinline__ float silu_f(float t) { return t / (1.f + __expf(-t)); }

// batch->XCD bijective block swizzle (800 % 8 == 0): batch b runs on blocks
// with blockIdx%8 == b, so y1t/zt slices stay in one XCD's L2 across kernels.
__device__ __forceinline__ int remap800(int blk) { return (blk & 7) * 100 + (blk >> 3); }

// ---------------- prep: BN-fold + bf16 A-fragment prepack -------------------
__global__ __launch_bounds__(256) void k_prep(
    const float* __restrict__ cv1w, const float* __restrict__ g1, const float* __restrict__ b1,
    const float* __restrict__ m1, const float* __restrict__ v1,
    const float* __restrict__ offw, const float* __restrict__ offb,
    const float* __restrict__ dcnw, const float* __restrict__ dcnb,
    const float* __restrict__ g2, const float* __restrict__ b2,
    const float* __restrict__ m2, const float* __restrict__ v2,
    const float* __restrict__ cv2w, const float* __restrict__ g3, const float* __restrict__ b3,
    const float* __restrict__ m3, const float* __restrict__ v3,
    unsigned short* __restrict__ apk1, unsigned short* __restrict__ apko,
    unsigned short* __restrict__ apkd, unsigned short* __restrict__ apk2,
    float* __restrict__ bias1, float* __restrict__ biaso,
    float* __restrict__ bias2, float* __restrict__ bias3)
{
    int idx = blockIdx.x * 256 + threadIdx.x;
    if (idx < 32768) {                       // cv1: [8 mt][8 ks][64][8], K = 256 ch
        int j = idx & 7, L = (idx >> 3) & 63, ks = (idx >> 9) & 7, mt = idx >> 12;
        int o = mt * 16 + (L & 15), k = ks * 32 + (L >> 4) * 8 + j;
        float inv = g1[o] * rsqrtf(v1[o] + BEPS);
        apk1[idx] = f2b(cv1w[o * 256 + k] * inv);
    } else if (idx < 69632) {                // off: [2 mt][36 ks][64][8], k' = n*128+c
        int t = idx - 32768;
        int j = t & 7, L = (t >> 3) & 63;
        int mt = t / 18432, rem = t % 18432, ks = rem >> 9;
        int o = mt * 16 + (L & 15);
        int kp = ks * 32 + (L >> 4) * 8 + j;
        int n = kp >> 7, c = kp & 127;
        float wv = (o < 27) ? offw[(size_t)(o * 128 + c) * 9 + n] : 0.f;
        apko[t] = f2b(wv);
    } else if (idx < 217088) {               // dcn: [8 mt][36 ks][64][8], k' = n*128+c, BN2 fold
        int t = idx - 69632;
        int j = t & 7, L = (t >> 3) & 63;
        int mt = t / 18432, rem = t % 18432, ks = rem >> 9;
        int o = mt * 16 + (L & 15);
        int kp = ks * 32 + (L >> 4) * 8 + j;
        int n = kp >> 7, c = kp & 127;
        float inv = g2[o] * rsqrtf(v2[o] + BEPS);
        apkd[t] = f2b(dcnw[(size_t)(o * 128 + c) * 9 + n] * inv);
    } else if (idx < 249856) {               // cv2: [16 mt][4 ks][64][8], BN3 fold
        int t = idx - 217088;
        int j = t & 7, L = (t >> 3) & 63, ks = (t >> 9) & 3, mt = t >> 11;
        int o = mt * 16 + (L & 15), k = ks * 32 + (L >> 4) * 8 + j;
        float inv = g3[o] * rsqrtf(v3[o] + BEPS);
        apk2[t] = f2b(cv2w[o * 128 + k] * inv);
    } else if (idx < 250395) {               // biases
        int t = idx - 249856;
        if (t < 128) { float inv = g1[t] * rsqrtf(v1[t] + BEPS); bias1[t] = b1[t] - m1[t] * inv; }
        else if (t < 155) { biaso[t - 128] = offb[t - 128]; }
        else if (t < 283) { int o = t - 155; float inv = g2[o] * rsqrtf(v2[o] + BEPS);
                            bias2[o] = dcnb[o] * inv + b2[o] - m2[o] * inv; }
        else { int o = t - 283; float inv = g3[o] * rsqrtf(v3[o] + BEPS); bias3[o] = b3[o] - m3[o] * inv; }
    }
}

// ---------------- cv1: 1x1 (256->128) + bn1 + silu -> y1t (pixel-major bf16) ----
__global__ __launch_bounds__(256) void k_cv1(
    const float* __restrict__ x, const unsigned short* __restrict__ apk1,
    const float* __restrict__ bias1, unsigned short* __restrict__ y1t)
{
    __shared__ __align__(16) unsigned short sB[20480];   // 8 ks * 4 nt * 16 * 40
    int blk = remap800(blockIdx.x);
    int b = blk / 100, pt = blk % 100;
    int p0 = pt * 64;
    int tid = threadIdx.x;
    int lane = tid & 63;
    int w = tid >> 6;
    {
        int px = lane, q = w;
        const float* xb = x + (size_t)b * 256 * HWSZ + p0 + px;
        for (int ks = 0; ks < 8; ++ks) {
            short8 v;
#pragma unroll
            for (int j = 0; j < 8; ++j)
                v[j] = (short)f2b(xb[(size_t)(ks * 32 + q * 8 + j) * HWSZ]);
            *(short8*)&sB[((ks * 4 + (px >> 4)) * 16 + (px & 15)) * 40 + q * 8] = v;
        }
    }
    __syncthreads();
    int n16 = lane & 15, qd = lane >> 4;
    f32x4 acc[2][4];
#pragma unroll
    for (int mi = 0; mi < 2; ++mi)
#pragma unroll
        for (int nt = 0; nt < 4; ++nt) acc[mi][nt] = (f32x4){0.f, 0.f, 0.f, 0.f};
    for (int ks = 0; ks < 8; ++ks) {
        short8 bf[4];
#pragma unroll
        for (int nt = 0; nt < 4; ++nt)
            bf[nt] = *(const short8*)&sB[((ks * 4 + nt) * 16 + n16) * 40 + qd * 8];
#pragma unroll
        for (int mi = 0; mi < 2; ++mi) {
            int mt = w * 2 + mi;
            short8 af = *(const short8*)&apk1[(size_t)((mt * 8 + ks) * 64 + lane) * 8];
#pragma unroll
            for (int nt = 0; nt < 4; ++nt)
                acc[mi][nt] = __builtin_amdgcn_mfma_f32_16x16x32_bf16(af, bf[nt], acc[mi][nt], 0, 0, 0);
        }
    }
    __syncthreads();
#pragma unroll
    for (int mi = 0; mi < 2; ++mi)
#pragma unroll
        for (int nt = 0; nt < 4; ++nt)
#pragma unroll
            for (int r = 0; r < 4; ++r) {
                int o = w * 32 + mi * 16 + qd * 4 + r;
                float sv = silu_f(acc[mi][nt][r] + bias1[o]);
                sB[(nt * 16 + n16) * 136 + o] = f2b(sv);
            }
    __syncthreads();
    {
        int px = tid >> 2, qq = tid & 3;
        unsigned short* ytb = y1t + ((size_t)b * HWSZ + p0 + px) * 128;
#pragma unroll
        for (int seg = 0; seg < 4; ++seg) {
            short8 v = *(const short8*)&sB[px * 136 + qq * 32 + seg * 8];
            *(short8*)&ytb[qq * 32 + seg * 8] = v;
        }
    }
}

// ---------------- off: 3x3 conv (128->27) + bias, sigmoid on mask ------------
__global__ __launch_bounds__(256) void k_off(
    const unsigned short* __restrict__ y1t, const unsigned short* __restrict__ apko,
    const float* __restrict__ biaso, float* __restrict__ raw)
{
    __shared__ __align__(16) unsigned short sV[227 * 136];   // 61,744 B
    int blk = remap800(blockIdx.x);
    int b = blk / 100, pt = blk % 100;
    int p0 = pt * 64;
    int tid = threadIdx.x;
    const unsigned short* yb = y1t + (size_t)b * HWSZ * 128;
    for (int c = tid; c < 226 * 16; c += 256) {
        int row = c >> 4, col = c & 15;
        int sp = p0 - 81 + row;
        sp = min(max(sp, 0), HWSZ - 1);
        *(short8*)&sV[row * 136 + col * 8] = *(const short8*)&yb[(size_t)sp * 128 + col * 8];
    }
    if (tid < 16) {
        short8 z = {0, 0, 0, 0, 0, 0, 0, 0};
        *(short8*)&sV[226 * 136 + tid * 8] = z;
    }
    __syncthreads();

    int lane = tid & 63, w = tid >> 6;
    int n16 = lane & 15, qd = lane >> 4;
    int p = p0 + w * 16 + n16;
    int h = p / WIMG, wx = p % WIMG;
    f32x4 acc[2];
    acc[0] = (f32x4){0.f, 0.f, 0.f, 0.f};
    acc[1] = (f32x4){0.f, 0.f, 0.f, 0.f};
#pragma unroll
    for (int n = 0; n < 9; ++n) {
        int dh = n / 3 - 1, dw = n % 3 - 1;
        int hh = h + dh, ww = wx + dw;
        bool valid = ((unsigned)hh < HIMG) && ((unsigned)ww < WIMG);
        int row = valid ? (81 + w * 16 + n16 + dh * WIMG + dw) : 226;
        const unsigned short* rV = &sV[row * 136 + qd * 8];
#pragma unroll
        for (int s = 0; s < 4; ++s) {
            int ks = n * 4 + s;
            short8 bf = *(const short8*)&rV[s * 32];
#pragma unroll
            for (int mi = 0; mi < 2; ++mi) {
                short8 af = *(const short8*)&apko[(size_t)((mi * 36 + ks) * 64 + lane) * 8];
                acc[mi] = __builtin_amdgcn_mfma_f32_16x16x32_bf16(af, bf, acc[mi], 0, 0, 0);
            }
        }
    }
    float* rb = raw + (size_t)b * 27 * HWSZ + p0 + w * 16 + n16;
#pragma unroll
    for (int mi = 0; mi < 2; ++mi)
#pragma unroll
        for (int r = 0; r < 4; ++r) {
            int o = mi * 16 + qd * 4 + r;
            if (o < 27) {
                float t = acc[mi][r] + biaso[o];
                if (o >= 18) t = 1.f / (1.f + __expf(-t));
                rb[(size_t)o * HWSZ] = t;
            }
        }
}

// ---------------- dcn: DCNv2 + bn2 + silu -> zt (pixel-major bf16) -----------
// 8x8 pixel tile + +/-2 halo (12x12 rows) staged ONCE in LDS (XOR-swizzled
// pitch-128); bilinear gather reads LDS, rare global fallback when an offset
// leaves the halo. 2 all-LDS barriers/tap. 63.1 KB static LDS -> 2 blocks/CU.
#define HY 12
#define HX 12
#define NHALO 144

#define ACC8(uu, cb)                                                                   \
    {                                                                                  \
        _Pragma("unroll") for (int t = 0; t < 4; ++t) {                                \
            unsigned uv = (uu)[t];                                                     \
            av[(cb) + 2 * t] = fmaf(wk, __builtin_bit_cast(float, uv << 16),           \
                                    av[(cb) + 2 * t]);                                 \
            av[(cb) + 2 * t + 1] = fmaf(wk, __builtin_bit_cast(float, uv & 0xffff0000u),\
                                        av[(cb) + 2 * t + 1]);                         \
        }                                                                              \
    }

__global__ __launch_bounds__(256, 2) void k_dcn(
    const unsigned short* __restrict__ y1t, const float* __restrict__ raw,
    const unsigned short* __restrict__ apkd, const float* __restrict__ bias2,
    unsigned short* __restrict__ zt)
{
    __shared__ __align__(16) unsigned short sH[NHALO * 128];   // 36,864 B halo (XOR swz)
    __shared__ __align__(16) unsigned short sB[64 * 136];      // 17,408 B B-tile
    __shared__ float swy[2][9][64];                            //  4,608 B (1-fy)*mk, fy*mk
    __shared__ unsigned short sfx[9][64];                      //  1,152 B fx as f16
    __shared__ unsigned short sidx[4][9][64];                  //  4,608 B yc*128+xc | valid<<15

    int blk = remap800(blockIdx.x);
    int b = blk / 100, pt = blk % 100;
    int h0 = (pt / 10) * 8, w0 = (pt % 10) * 8;
    int tid = threadIdx.x;
    const unsigned short* yb = y1t + (size_t)b * HWSZ * 128;

    // stage halo: 144 rows x 256B, contiguous 16B units, XOR-swizzled dest
    for (int i = tid; i < NHALO * 16; i += 256) {
        int r = i >> 4, u = i & 15;
        int ly = r / HX, lx = r % HX;
        int yy = min(max(h0 + ly - 2, 0), HIMG - 1);
        int xx = min(max(w0 + lx - 2, 0), WIMG - 1);
        *(u32x4*)&sH[r * 128 + (u ^ (r & 7)) * 8] =
            *(const u32x4*)&yb[(size_t)(yy * WIMG + xx) * 128 + u * 8];
    }
    // decode offsets -> compact per-(tap,pixel) records
    for (int i = tid; i < 576; i += 256) {
        int n = i / 64, pp = i & 63;
        int h = h0 + (pp >> 3), wx = w0 + (pp & 7);
        int p = h * WIMG + wx;
        const float* rb = raw + (size_t)b * 27 * HWSZ + p;
        float dy = rb[(size_t)(2 * n) * HWSZ];
        float dx = rb[(size_t)(2 * n + 1) * HWSZ];
        float mk = rb[(size_t)(18 + n) * HWSZ];
        float py = (float)(h - 1 + n / 3) + dy;
        float px = (float)(wx - 1 + n % 3) + dx;
        float y0f = floorf(py), x0f = floorf(px);
        float fy = py - y0f, fx = px - x0f;
        int y0 = (int)y0f, x0 = (int)x0f;
        swy[0][n][pp] = (1.f - fy) * mk;
        swy[1][n][pp] = fy * mk;
        sfx[n][pp] = __builtin_bit_cast(unsigned short, (_Float16)fx);
#pragma unroll
        for (int k = 0; k < 4; ++k) {
            int yy = y0 + (k >> 1);
            int xx = x0 + (k & 1);
            unsigned valid = (((unsigned)yy < HIMG) && ((unsigned)xx < WIMG)) ? 0x8000u : 0u;
            int yc = min(max(yy, 0), HIMG - 1);
            int xc = min(max(xx, 0), WIMG - 1);
            sidx[k][n][pp] = (unsigned short)((yc << 7) | xc | valid);
        }
    }
    __syncthreads();

    int lane = tid & 63, w = tid >> 6;
    int n16 = lane & 15, qd = lane >> 4;
    int pxl = tid >> 2, q = tid & 3;          // 64 px x 4 thr, 32 ch each
    f32x4 acc[2][4];
#pragma unroll
    for (int mi = 0; mi < 2; ++mi)
#pragma unroll
        for (int nt = 0; nt < 4; ++nt) acc[mi][nt] = (f32x4){0.f, 0.f, 0.f, 0.f};

    for (int n = 0; n < 9; ++n) {
        float av[32];
#pragma unroll
        for (int j = 0; j < 32; ++j) av[j] = 0.f;
        float fxv = (float)__builtin_bit_cast(_Float16, sfx[n][pxl]);
        float fx1 = 1.f - fxv;
        float wy0 = swy[0][n][pxl], wy1 = swy[1][n][pxl];
#pragma unroll
        for (int k = 0; k < 4; ++k) {
            unsigned s = sidx[k][n][pxl];
            float wk = ((k >> 1) ? wy1 : wy0) * ((k & 1) ? fxv : fx1);
            if (!(s & 0x8000u)) wk = 0.f;
            int yc = (int)((s >> 7) & 127u), xc = (int)(s & 127u);
            int ly = yc - h0 + 2, lx = xc - w0 + 2;
            if (((unsigned)ly < HY) && ((unsigned)lx < HX)) {
                int r = ly * HX + lx;
                const unsigned short* hb = &sH[r * 128];
                int xr = r & 7;
                u32x4 u0 = *(const u32x4*)&hb[((q * 4 + 0) ^ xr) * 8];
                u32x4 u1 = *(const u32x4*)&hb[((q * 4 + 1) ^ xr) * 8];
                u32x4 u2 = *(const u32x4*)&hb[((q * 4 + 2) ^ xr) * 8];
                u32x4 u3 = *(const u32x4*)&hb[((q * 4 + 3) ^ xr) * 8];
                ACC8(u0, 0) ACC8(u1, 8) ACC8(u2, 16) ACC8(u3, 24)
            } else if (wk != 0.f) {            // rare: offset beyond halo
                const unsigned short* src = &yb[(size_t)(yc * WIMG + xc) * 128 + q * 32];
                u32x4 u0 = *(const u32x4*)src;
                u32x4 u1 = *(const u32x4*)(src + 8);
                u32x4 u2 = *(const u32x4*)(src + 16);
                u32x4 u3 = *(const u32x4*)(src + 24);
                ACC8(u0, 0) ACC8(u1, 8) ACC8(u2, 16) ACC8(u3, 24)
            }
        }
        unsigned pk[16];
#pragma unroll
        for (int t = 0; t < 16; ++t)
            asm("v_cvt_pk_bf16_f32 %0, %1, %2" : "=v"(pk[t]) : "v"(av[2 * t]), "v"(av[2 * t + 1]));
        {
            unsigned short* dst = &sB[pxl * 136 + q * 32];
            *(u32x4*)dst        = (u32x4){pk[0], pk[1], pk[2], pk[3]};
            *(u32x4*)(dst + 8)  = (u32x4){pk[4], pk[5], pk[6], pk[7]};
            *(u32x4*)(dst + 16) = (u32x4){pk[8], pk[9], pk[10], pk[11]};
            *(u32x4*)(dst + 24) = (u32x4){pk[12], pk[13], pk[14], pk[15]};
        }
        __syncthreads();
#pragma unroll
        for (int sub = 0; sub < 4; ++sub) {
            int ks = n * 4 + sub;
            short8 bf[4];
#pragma unroll
            for (int nt = 0; nt < 4; ++nt)
                bf[nt] = *(const short8*)&sB[(nt * 16 + n16) * 136 + sub * 32 + qd * 8];
#pragma unroll
            for (int mi = 0; mi < 2; ++mi) {
                short8 af = *(const short8*)&apkd[(size_t)(((2 * w + mi) * 36 + ks) * 64 + lane) * 8];
#pragma unroll
                for (int nt = 0; nt < 4; ++nt)
                    acc[mi][nt] = __builtin_amdgcn_mfma_f32_16x16x32_bf16(af, bf[nt], acc[mi][nt], 0, 0, 0);
            }
        }
        __syncthreads();
    }
    // epilogue: bn2(fused)+silu, transpose to pixel-major bf16 via sB
#pragma unroll
    for (int mi = 0; mi < 2; ++mi)
#pragma unroll
        for (int nt = 0; nt < 4; ++nt)
#pragma unroll
            for (int r = 0; r < 4; ++r) {
                int o = w * 32 + mi * 16 + qd * 4 + r;
                float sv = silu_f(acc[mi][nt][r] + bias2[o]);
                sB[(nt * 16 + n16) * 136 + o] = f2b(sv);
            }
    __syncthreads();
    {
        int px = tid >> 2, qq = tid & 3;
        int p = (h0 + (px >> 3)) * WIMG + w0 + (px & 7);
        unsigned short* zb = zt + ((size_t)b * HWSZ + p) * 128;
#pragma unroll
        for (int seg = 0; seg < 4; ++seg) {
            short8 v = *(const short8*)&sB[px * 136 + qq * 32 + seg * 8];
            *(short8*)&zb[qq * 32 + seg * 8] = v;
        }
    }
}

// ---------------- cv2: 1x1 (128->256) + bn3 + silu + residual ----------------
__global__ __launch_bounds__(256) void k_cv2(
    const unsigned short* __restrict__ zt, const float* __restrict__ x,
    const unsigned short* __restrict__ apk2, const float* __restrict__ bias3,
    float* __restrict__ out)
{
    int blk = remap800(blockIdx.x);
    int b = blk / 100, pt = blk % 100;
    int p0 = pt * 64;
    int tid = threadIdx.x;
    int lane = tid & 63, w = tid >> 6;
    int n16 = lane & 15, qd = lane >> 4;
    const unsigned short* zb = zt + ((size_t)b * HWSZ + p0) * 128;
    f32x4 acc[4][4];
#pragma unroll
    for (int mi = 0; mi < 4; ++mi)
#pragma unroll
        for (int nt = 0; nt < 4; ++nt) acc[mi][nt] = (f32x4){0.f, 0.f, 0.f, 0.f};
#pragma unroll
    for (int ks = 0; ks < 4; ++ks) {
        short8 bf[4];
#pragma unroll
        for (int nt = 0; nt < 4; ++nt)
            bf[nt] = *(const short8*)&zb[(size_t)(nt * 16 + n16) * 128 + ks * 32 + qd * 8];
#pragma unroll
        for (int mi = 0; mi < 4; ++mi) {
            int mt = w * 4 + mi;
            short8 af = *(const short8*)&apk2[(size_t)((mt * 4 + ks) * 64 + lane) * 8];
#pragma unroll
            for (int nt = 0; nt < 4; ++nt)
                acc[mi][nt] = __builtin_amdgcn_mfma_f32_16x16x32_bf16(af, bf[nt], acc[mi][nt], 0, 0, 0);
        }
    }
    const float* xb = x + (size_t)b * 256 * HWSZ;
    float* ob = out + (size_t)b * 256 * HWSZ;
#pragma unroll
    for (int mi = 0; mi < 4; ++mi)
#pragma unroll
        for (int nt = 0; nt < 4; ++nt)
#pragma unroll
            for (int r = 0; r < 4; ++r) {
                int o = w * 64 + mi * 16 + qd * 4 + r;
                size_t idx = (size_t)o * HWSZ + p0 + nt * 16 + n16;
                ob[idx] = xb[idx] + silu_f(acc[mi][nt][r] + bias3[o]);
            }
}

extern "C" void kernel_launch(void* const* d_in, const int* in_sizes, int n_in,
                              void* d_out, int out_size, void* d_ws, size_t ws_size,
                              hipStream_t stream) {
    const float* x     = (const float*)d_in[0];
    const float* cv1w  = (const float*)d_in[1];
    const float* bn1g  = (const float*)d_in[2];
    const float* bn1b  = (const float*)d_in[3];
    const float* bn1m  = (const float*)d_in[4];
    const float* bn1v  = (const float*)d_in[5];
    const float* offw  = (const float*)d_in[6];
    const float* offb  = (const float*)d_in[7];
    const float* dcnw  = (const float*)d_in[8];
    const float* dcnb  = (const float*)d_in[9];
    const float* bn2g  = (const float*)d_in[10];
    const float* bn2b  = (const float*)d_in[11];
    const float* bn2m  = (const float*)d_in[12];
    const float* bn2v  = (const float*)d_in[13];
    const float* cv2w  = (const float*)d_in[14];
    const float* bn3g  = (const float*)d_in[15];
    const float* bn3b  = (const float*)d_in[16];
    const float* bn3m  = (const float*)d_in[17];
    const float* bn3v  = (const float*)d_in[18];
    float* out = (float*)d_out;

    // workspace layout (float units)
    float* base = (float*)d_ws;
    unsigned short* y1t = (unsigned short*)base;                 // 8*6400*128 bf16
    float* raw   = base + 3276800;                               // 8*27*6400
    unsigned short* zt  = (unsigned short*)(base + 4659200);     // 8*6400*128 bf16
    unsigned short* apk1 = (unsigned short*)(base + 7936000);
    unsigned short* apko = (unsigned short*)(base + 7952384);
    unsigned short* apkd = (unsigned short*)(base + 7970816);
    unsigned short* apk2 = (unsigned short*)(base + 8044544);
    float* bias1 = base + 8060928;
    float* biaso = base + 8061056;
    float* bias2 = base + 8061088;
    float* bias3 = base + 8061216;

    k_prep<<<979, 256, 0, stream>>>(cv1w, bn1g, bn1b, bn1m, bn1v,
                                    offw, offb, dcnw, dcnb,
                                    bn2g, bn2b, bn2m, bn2v,
                                    cv2w, bn3g, bn3b, bn3m, bn3v,
                                    apk1, apko, apkd, apk2,
                                    bias1, biaso, bias2, bias3);
    k_cv1<<<800, 256, 0, stream>>>(x, apk1, bias1, y1t);
    k_off<<<800, 256, 0, stream>>>(y1t, apko, biaso, raw);
    k_dcn<<<800, 256, 0, stream>>>(y1t, raw, apkd, bias2, zt);
    k_cv2<<<800, 256, 0, stream>>>(zt, x, apk2, bias3, out);
}

// Round 4
// 245.756 us; speedup vs baseline: 1.0695x; 1.0695x over previous
//
#include <hip/hip_runtime.h>
#include <math.h>

#define HWSZ 6400
#define WIMG 80
#define HIMG 80
#define BEPS 1e-5f

typedef __attribute__((ext_vector_type(8))) short short8;
typedef __attribute__((ext_vector_type(4))) float f32x4;
typedef __attribute__((ext_vector_type(4))) unsigned u32x4;

__device__ __forceinline__ unsigned short f2b(float f) {
    unsigned u = __builtin_bit_cast(unsigned, f);
    u += 0x7fffu + ((u >> 16) & 1u);
    return (unsigned short)(u >> 16);
}
__device__ __forceinline__ float b2f(unsigned short h) {
    unsigned u = ((unsigned)h) << 16;
    return __builtin_bit_cast(float, u);
}
__device__ __forceinline__ float silu_f(float t) { return t / (1.f + __expf(-t)); }

// ---------------- prep: BN-fold + bf16 A-fragment prepack -------------------
__global__ __launch_bounds__(256) void k_prep(
    const float* __restrict__ cv1w, const float* __restrict__ g1, const float* __restrict__ b1,
    const float* __restrict__ m1, const float* __restrict__ v1,
    const float* __restrict__ offw, const float* __restrict__ offb,
    const float* __restrict__ dcnw, const float* __restrict__ dcnb,
    const float* __restrict__ g2, const float* __restrict__ b2,
    const float* __restrict__ m2, const float* __restrict__ v2,
    const float* __restrict__ cv2w, const float* __restrict__ g3, const float* __restrict__ b3,
    const float* __restrict__ m3, const float* __restrict__ v3,
    unsigned short* __restrict__ apk1, unsigned short* __restrict__ apko,
    unsigned short* __restrict__ apkd, unsigned short* __restrict__ apk2,
    float* __restrict__ bias1, float* __restrict__ biaso,
    float* __restrict__ bias2, float* __restrict__ bias3)
{
    int idx = blockIdx.x * 256 + threadIdx.x;
    if (idx < 32768) {                       // cv1: [8 mt][8 ks][64][8], K = 256 ch
        int j = idx & 7, L = (idx >> 3) & 63, ks = (idx >> 9) & 7, mt = idx >> 12;
        int o = mt * 16 + (L & 15), k = ks * 32 + (L >> 4) * 8 + j;
        float inv = g1[o] * rsqrtf(v1[o] + BEPS);
        apk1[idx] = f2b(cv1w[o * 256 + k] * inv);
    } else if (idx < 69632) {                // off: [2 mt][36 ks][64][8], k' = n*128+c
        int t = idx - 32768;
        int j = t & 7, L = (t >> 3) & 63;
        int mt = t / 18432, rem = t % 18432, ks = rem >> 9;
        int o = mt * 16 + (L & 15);
        int kp = ks * 32 + (L >> 4) * 8 + j;
        int n = kp >> 7, c = kp & 127;
        float wv = (o < 27) ? offw[(size_t)(o * 128 + c) * 9 + n] : 0.f;
        apko[t] = f2b(wv);
    } else if (idx < 217088) {               // dcn: [8 mt][36 ks][64][8], k' = n*128+c, BN2 fold
        int t = idx - 69632;
        int j = t & 7, L = (t >> 3) & 63;
        int mt = t / 18432, rem = t % 18432, ks = rem >> 9;
        int o = mt * 16 + (L & 15);
        int kp = ks * 32 + (L >> 4) * 8 + j;
        int n = kp >> 7, c = kp & 127;
        float inv = g2[o] * rsqrtf(v2[o] + BEPS);
        apkd[t] = f2b(dcnw[(size_t)(o * 128 + c) * 9 + n] * inv);
    } else if (idx < 249856) {               // cv2: [16 mt][4 ks][64][8], BN3 fold
        int t = idx - 217088;
        int j = t & 7, L = (t >> 3) & 63, ks = (t >> 9) & 3, mt = t >> 11;
        int o = mt * 16 + (L & 15), k = ks * 32 + (L >> 4) * 8 + j;
        float inv = g3[o] * rsqrtf(v3[o] + BEPS);
        apk2[t] = f2b(cv2w[o * 128 + k] * inv);
    } else if (idx < 250395) {               // biases
        int t = idx - 249856;
        if (t < 128) { float inv = g1[t] * rsqrtf(v1[t] + BEPS); bias1[t] = b1[t] - m1[t] * inv; }
        else if (t < 155) { biaso[t - 128] = offb[t - 128]; }
        else if (t < 283) { int o = t - 155; float inv = g2[o] * rsqrtf(v2[o] + BEPS);
                            bias2[o] = dcnb[o] * inv + b2[o] - m2[o] * inv; }
        else { int o = t - 283; float inv = g3[o] * rsqrtf(v3[o] + BEPS); bias3[o] = b3[o] - m3[o] * inv; }
    }
}

// ---------------- cv1: 1x1 (256->128) + bn1 + silu -> y1t (pixel-major bf16) ----
__global__ __launch_bounds__(256) void k_cv1(
    const float* __restrict__ x, const unsigned short* __restrict__ apk1,
    const float* __restrict__ bias1, unsigned short* __restrict__ y1t)
{
    __shared__ __align__(16) unsigned short sB[20480];   // 8 ks * 4 nt * 16 * 40
    int blk = blockIdx.x;
    int b = blk / 100, pt = blk % 100;
    int p0 = pt * 64;
    int tid = threadIdx.x;
    int lane = tid & 63;
    int w = tid >> 6;
    {
        int px = lane, q = w;
        const float* xb = x + (size_t)b * 256 * HWSZ + p0 + px;
        for (int ks = 0; ks < 8; ++ks) {
            unsigned pk[4];
#pragma unroll
            for (int t = 0; t < 4; ++t) {
                float f0 = xb[(size_t)(ks * 32 + q * 8 + 2 * t) * HWSZ];
                float f1 = xb[(size_t)(ks * 32 + q * 8 + 2 * t + 1) * HWSZ];
                asm("v_cvt_pk_bf16_f32 %0, %1, %2" : "=v"(pk[t]) : "v"(f0), "v"(f1));
            }
            *(u32x4*)&sB[((ks * 4 + (px >> 4)) * 16 + (px & 15)) * 40 + q * 8] =
                (u32x4){pk[0], pk[1], pk[2], pk[3]};
        }
    }
    __syncthreads();
    int n16 = lane & 15, qd = lane >> 4;
    f32x4 acc[2][4];
#pragma unroll
    for (int mi = 0; mi < 2; ++mi)
#pragma unroll
        for (int nt = 0; nt < 4; ++nt) acc[mi][nt] = (f32x4){0.f, 0.f, 0.f, 0.f};
    for (int ks = 0; ks < 8; ++ks) {
        short8 bf[4];
#pragma unroll
        for (int nt = 0; nt < 4; ++nt)
            bf[nt] = *(const short8*)&sB[((ks * 4 + nt) * 16 + n16) * 40 + qd * 8];
#pragma unroll
        for (int mi = 0; mi < 2; ++mi) {
            int mt = w * 2 + mi;
            short8 af = *(const short8*)&apk1[(size_t)((mt * 8 + ks) * 64 + lane) * 8];
#pragma unroll
            for (int nt = 0; nt < 4; ++nt)
                acc[mi][nt] = __builtin_amdgcn_mfma_f32_16x16x32_bf16(af, bf[nt], acc[mi][nt], 0, 0, 0);
        }
    }
    __syncthreads();
#pragma unroll
    for (int mi = 0; mi < 2; ++mi)
#pragma unroll
        for (int nt = 0; nt < 4; ++nt)
#pragma unroll
            for (int r = 0; r < 4; ++r) {
                int o = w * 32 + mi * 16 + qd * 4 + r;
                float sv = silu_f(acc[mi][nt][r] + bias1[o]);
                sB[(nt * 16 + n16) * 136 + o] = f2b(sv);
            }
    __syncthreads();
    {
        int px = tid >> 2, qq = tid & 3;
        unsigned short* ytb = y1t + ((size_t)b * HWSZ + p0 + px) * 128;
#pragma unroll
        for (int seg = 0; seg < 4; ++seg) {
            short8 v = *(const short8*)&sB[px * 136 + qq * 32 + seg * 8];
            *(short8*)&ytb[qq * 32 + seg * 8] = v;
        }
    }
}

// ---------------- off: 3x3 conv (128->27) + bias, sigmoid on mask ------------
__global__ __launch_bounds__(256) void k_off(
    const unsigned short* __restrict__ y1t, const unsigned short* __restrict__ apko,
    const float* __restrict__ biaso, float* __restrict__ raw)
{
    __shared__ __align__(16) unsigned short sV[227 * 136];   // 61,744 B
    int blk = blockIdx.x;
    int b = blk / 100, pt = blk % 100;
    int p0 = pt * 64;
    int tid = threadIdx.x;
    const unsigned short* yb = y1t + (size_t)b * HWSZ * 128;
    for (int c = tid; c < 226 * 16; c += 256) {
        int row = c >> 4, col = c & 15;
        int sp = p0 - 81 + row;
        sp = min(max(sp, 0), HWSZ - 1);
        *(short8*)&sV[row * 136 + col * 8] = *(const short8*)&yb[(size_t)sp * 128 + col * 8];
    }
    if (tid < 16) {
        short8 z = {0, 0, 0, 0, 0, 0, 0, 0};
        *(short8*)&sV[226 * 136 + tid * 8] = z;
    }
    __syncthreads();

    int lane = tid & 63, w = tid >> 6;
    int n16 = lane & 15, qd = lane >> 4;
    int p = p0 + w * 16 + n16;
    int h = p / WIMG, wx = p % WIMG;
    f32x4 acc[2];
    acc[0] = (f32x4){0.f, 0.f, 0.f, 0.f};
    acc[1] = (f32x4){0.f, 0.f, 0.f, 0.f};
#pragma unroll
    for (int n = 0; n < 9; ++n) {
        int dh = n / 3 - 1, dw = n % 3 - 1;
        int hh = h + dh, ww = wx + dw;
        bool valid = ((unsigned)hh < HIMG) && ((unsigned)ww < WIMG);
        int row = valid ? (81 + w * 16 + n16 + dh * WIMG + dw) : 226;
        const unsigned short* rV = &sV[row * 136 + qd * 8];
#pragma unroll
        for (int s = 0; s < 4; ++s) {
            int ks = n * 4 + s;
            short8 bf = *(const short8*)&rV[s * 32];
#pragma unroll
            for (int mi = 0; mi < 2; ++mi) {
                short8 af = *(const short8*)&apko[(size_t)((mi * 36 + ks) * 64 + lane) * 8];
                acc[mi] = __builtin_amdgcn_mfma_f32_16x16x32_bf16(af, bf, acc[mi], 0, 0, 0);
            }
        }
    }
    float* rb = raw + (size_t)b * 27 * HWSZ + p0 + w * 16 + n16;
#pragma unroll
    for (int mi = 0; mi < 2; ++mi)
#pragma unroll
        for (int r = 0; r < 4; ++r) {
            int o = mi * 16 + qd * 4 + r;
            if (o < 27) {
                float t = acc[mi][r] + biaso[o];
                if (o >= 18) t = 1.f / (1.f + __expf(-t));
                rb[(size_t)o * HWSZ] = t;
            }
        }
}

// ---------------- dcn: DCNv2 + bn2 + silu -> zt (pixel-major bf16) -----------
// Barrier-free tap loop: each wave owns full M=128 x its own N=16 pixels.
// Lane gathers ITS OWN B-fragment channels (qd*8+j of pixel n16) from the LDS
// halo, cvt_pk's to bf16 in-register, feeds MFMA directly. No B-tile in LDS,
// no intra-tap barriers; A-frags stream from L2. 47.2 KB LDS -> 3 blocks/CU.
#define HY 12
#define HX 12
#define NHALO 144

#define ACC8(uu, cb)                                                                   \
    {                                                                                  \
        _Pragma("unroll") for (int t = 0; t < 4; ++t) {                                \
            unsigned uv = (uu)[t];                                                     \
            av[(cb) + 2 * t] = fmaf(wk, __builtin_bit_cast(float, uv << 16),           \
                                    av[(cb) + 2 * t]);                                 \
            av[(cb) + 2 * t + 1] = fmaf(wk, __builtin_bit_cast(float, uv & 0xffff0000u),\
                                        av[(cb) + 2 * t + 1]);                         \
        }                                                                              \
    }

__global__ __launch_bounds__(256, 3) void k_dcn(
    const unsigned short* __restrict__ y1t, const float* __restrict__ raw,
    const unsigned short* __restrict__ apkd, const float* __restrict__ bias2,
    unsigned short* __restrict__ zt)
{
    __shared__ __align__(16) unsigned short sH[NHALO * 128];   // 36,864 B halo (XOR swz)
    __shared__ float swy[2][9][64];                            //  4,608 B
    __shared__ unsigned short sfx[9][64];                      //  1,152 B
    __shared__ unsigned short sidx[4][9][64];                  //  4,608 B

    int blk = blockIdx.x;
    int b = blk / 100, pt = blk % 100;
    int h0 = (pt / 10) * 8, w0 = (pt % 10) * 8;
    int tid = threadIdx.x;
    const unsigned short* yb = y1t + (size_t)b * HWSZ * 128;

    // stage halo: 144 rows x 256B, contiguous 16B units, XOR-swizzled dest
    for (int i = tid; i < NHALO * 16; i += 256) {
        int r = i >> 4, u = i & 15;
        int ly = r / HX, lx = r % HX;
        int yy = min(max(h0 + ly - 2, 0), HIMG - 1);
        int xx = min(max(w0 + lx - 2, 0), WIMG - 1);
        *(u32x4*)&sH[r * 128 + (u ^ (r & 7)) * 8] =
            *(const u32x4*)&yb[(size_t)(yy * WIMG + xx) * 128 + u * 8];
    }
    // decode offsets -> compact per-(tap,pixel) records
    for (int i = tid; i < 576; i += 256) {
        int n = i / 64, pp = i & 63;
        int h = h0 + (pp >> 3), wx = w0 + (pp & 7);
        int p = h * WIMG + wx;
        const float* rb = raw + (size_t)b * 27 * HWSZ + p;
        float dy = rb[(size_t)(2 * n) * HWSZ];
        float dx = rb[(size_t)(2 * n + 1) * HWSZ];
        float mk = rb[(size_t)(18 + n) * HWSZ];
        float py = (float)(h - 1 + n / 3) + dy;
        float px = (float)(wx - 1 + n % 3) + dx;
        float y0f = floorf(py), x0f = floorf(px);
        float fy = py - y0f, fx = px - x0f;
        int y0 = (int)y0f, x0 = (int)x0f;
        swy[0][n][pp] = (1.f - fy) * mk;
        swy[1][n][pp] = fy * mk;
        sfx[n][pp] = __builtin_bit_cast(unsigned short, (_Float16)fx);
#pragma unroll
        for (int k = 0; k < 4; ++k) {
            int yy = y0 + (k >> 1);
            int xx = x0 + (k & 1);
            unsigned valid = (((unsigned)yy < HIMG) && ((unsigned)xx < WIMG)) ? 0x8000u : 0u;
            int yc = min(max(yy, 0), HIMG - 1);
            int xc = min(max(xx, 0), WIMG - 1);
            sidx[k][n][pp] = (unsigned short)((yc << 7) | xc | valid);
        }
    }
    __syncthreads();

    int lane = tid & 63, w = tid >> 6;
    int n16 = lane & 15, qd = lane >> 4;
    int pxl = w * 16 + n16;                 // this wave's pixel for this lane
    f32x4 acc[8];
#pragma unroll
    for (int mt = 0; mt < 8; ++mt) acc[mt] = (f32x4){0.f, 0.f, 0.f, 0.f};

    for (int n = 0; n < 9; ++n) {
        // gather 32 channels (qd*8 + s*32 + j) of pixel pxl into av[]
        float av[32];
#pragma unroll
        for (int j = 0; j < 32; ++j) av[j] = 0.f;
        float fxv = (float)__builtin_bit_cast(_Float16, sfx[n][pxl]);
        float fx1 = 1.f - fxv;
        float wy0 = swy[0][n][pxl], wy1 = swy[1][n][pxl];
#pragma unroll
        for (int k = 0; k < 4; ++k) {
            unsigned s = sidx[k][n][pxl];
            float wk = ((k >> 1) ? wy1 : wy0) * ((k & 1) ? fxv : fx1);
            if (!(s & 0x8000u)) wk = 0.f;
            int yc = (int)((s >> 7) & 127u), xc = (int)(s & 127u);
            int ly = yc - h0 + 2, lx = xc - w0 + 2;
            if (((unsigned)ly < HY) && ((unsigned)lx < HX)) {
                int r = ly * HX + lx;
                const unsigned short* hb = &sH[r * 128];
                int xr = r & 7;
                u32x4 u0 = *(const u32x4*)&hb[((qd) ^ xr) * 8];
                u32x4 u1 = *(const u32x4*)&hb[((4 + qd) ^ xr) * 8];
                u32x4 u2 = *(const u32x4*)&hb[((8 + qd) ^ xr) * 8];
                u32x4 u3 = *(const u32x4*)&hb[((12 + qd) ^ xr) * 8];
                ACC8(u0, 0) ACC8(u1, 8) ACC8(u2, 16) ACC8(u3, 24)
            } else if (wk != 0.f) {            // rare: offset beyond halo
                const unsigned short* src = &yb[(size_t)(yc * WIMG + xc) * 128 + qd * 8];
                u32x4 u0 = *(const u32x4*)src;
                u32x4 u1 = *(const u32x4*)(src + 32);
                u32x4 u2 = *(const u32x4*)(src + 64);
                u32x4 u3 = *(const u32x4*)(src + 96);
                ACC8(u0, 0) ACC8(u1, 8) ACC8(u2, 16) ACC8(u3, 24)
            }
        }
        // per 32-ch k-step: pack own B-frag, stream A-frags, 8 MFMA
#pragma unroll
        for (int s = 0; s < 4; ++s) {
            unsigned pk[4];
#pragma unroll
            for (int t = 0; t < 4; ++t)
                asm("v_cvt_pk_bf16_f32 %0, %1, %2"
                    : "=v"(pk[t]) : "v"(av[s * 8 + 2 * t]), "v"(av[s * 8 + 2 * t + 1]));
            short8 bf = __builtin_bit_cast(short8, (u32x4){pk[0], pk[1], pk[2], pk[3]});
            int ks = n * 4 + s;
            const unsigned short* ap = apkd + (size_t)(ks * 64 + lane) * 8;
#pragma unroll
            for (int mt = 0; mt < 8; ++mt) {
                short8 af = *(const short8*)&ap[(size_t)mt * 18432];
                acc[mt] = __builtin_amdgcn_mfma_f32_16x16x32_bf16(af, bf, acc[mt], 0, 0, 0);
            }
        }
    }
    __syncthreads();                         // all waves done reading sH
    // epilogue: bn2(fused)+silu, stage pixel-major via sH storage, store
    unsigned short* sE = sH;
#pragma unroll
    for (int mt = 0; mt < 8; ++mt)
#pragma unroll
        for (int r = 0; r < 4; ++r) {
            int o = mt * 16 + qd * 4 + r;
            float sv = silu_f(acc[mt][r] + bias2[o]);
            sE[pxl * 136 + o] = f2b(sv);
        }
    __syncthreads();
    {
        int px = tid >> 2, qq = tid & 3;
        int p = (h0 + (px >> 3)) * WIMG + w0 + (px & 7);
        unsigned short* zb = zt + ((size_t)b * HWSZ + p) * 128;
#pragma unroll
        for (int seg = 0; seg < 4; ++seg) {
            short8 v = *(const short8*)&sE[px * 136 + qq * 32 + seg * 8];
            *(short8*)&zb[qq * 32 + seg * 8] = v;
        }
    }
}

// ---------------- cv2: 1x1 (128->256) + bn3 + silu + residual ----------------
__global__ __launch_bounds__(256) void k_cv2(
    const unsigned short* __restrict__ zt, const float* __restrict__ x,
    const unsigned short* __restrict__ apk2, const float* __restrict__ bias3,
    float* __restrict__ out)
{
    int blk = blockIdx.x;
    int b = blk / 100, pt = blk % 100;
    int p0 = pt * 64;
    int tid = threadIdx.x;
    int lane = tid & 63, w = tid >> 6;
    int n16 = lane & 15, qd = lane >> 4;
    const unsigned short* zb = zt + ((size_t)b * HWSZ + p0) * 128;
    f32x4 acc[4][4];
#pragma unroll
    for (int mi = 0; mi < 4; ++mi)
#pragma unroll
        for (int nt = 0; nt < 4; ++nt) acc[mi][nt] = (f32x4){0.f, 0.f, 0.f, 0.f};
#pragma unroll
    for (int ks = 0; ks < 4; ++ks) {
        short8 bf[4];
#pragma unroll
        for (int nt = 0; nt < 4; ++nt)
            bf[nt] = *(const short8*)&zb[(size_t)(nt * 16 + n16) * 128 + ks * 32 + qd * 8];
#pragma unroll
        for (int mi = 0; mi < 4; ++mi) {
            int mt = w * 4 + mi;
            short8 af = *(const short8*)&apk2[(size_t)((mt * 4 + ks) * 64 + lane) * 8];
#pragma unroll
            for (int nt = 0; nt < 4; ++nt)
                acc[mi][nt] = __builtin_amdgcn_mfma_f32_16x16x32_bf16(af, bf[nt], acc[mi][nt], 0, 0, 0);
        }
    }
    const float* xb = x + (size_t)b * 256 * HWSZ;
    float* ob = out + (size_t)b * 256 * HWSZ;
#pragma unroll
    for (int mi = 0; mi < 4; ++mi)
#pragma unroll
        for (int nt = 0; nt < 4; ++nt)
#pragma unroll
            for (int r = 0; r < 4; ++r) {
                int o = w * 64 + mi * 16 + qd * 4 + r;
                size_t idx = (size_t)o * HWSZ + p0 + nt * 16 + n16;
                ob[idx] = xb[idx] + silu_f(acc[mi][nt][r] + bias3[o]);
            }
}

extern "C" void kernel_launch(void* const* d_in, const int* in_sizes, int n_in,
                              void* d_out, int out_size, void* d_ws, size_t ws_size,
                              hipStream_t stream) {
    const float* x     = (const float*)d_in[0];
    const float* cv1w  = (const float*)d_in[1];
    const float* bn1g  = (const float*)d_in[2];
    const float* bn1b  = (const float*)d_in[3];
    const float* bn1m  = (const float*)d_in[4];
    const float* bn1v  = (const float*)d_in[5];
    const float* offw  = (const float*)d_in[6];
    const float* offb  = (const float*)d_in[7];
    const float* dcnw  = (const float*)d_in[8];
    const float* dcnb  = (const float*)d_in[9];
    const float* bn2g  = (const float*)d_in[10];
    const float* bn2b  = (const float*)d_in[11];
    const float* bn2m  = (const float*)d_in[12];
    const float* bn2v  = (const float*)d_in[13];
    const float* cv2w  = (const float*)d_in[14];
    const float* bn3g  = (const float*)d_in[15];
    const float* bn3b  = (const float*)d_in[16];
    const float* bn3m  = (const float*)d_in[17];
    const float* bn3v  = (const float*)d_in[18];
    float* out = (float*)d_out;

    // workspace layout (float units)
    float* base = (float*)d_ws;
    unsigned short* y1t = (unsigned short*)base;                 // 8*6400*128 bf16
    float* raw   = base + 3276800;                               // 8*27*6400
    unsigned short* zt  = (unsigned short*)(base + 4659200);     // 8*6400*128 bf16
    unsigned short* apk1 = (unsigned short*)(base + 7936000);
    unsigned short* apko = (unsigned short*)(base + 7952384);
    unsigned short* apkd = (unsigned short*)(base + 7970816);
    unsigned short* apk2 = (unsigned short*)(base + 8044544);
    float* bias1 = base + 8060928;
    float* biaso = base + 8061056;
    float* bias2 = base + 8061088;
    float* bias3 = base + 8061216;

    k_prep<<<979, 256, 0, stream>>>(cv1w, bn1g, bn1b, bn1m, bn1v,
                                    offw, offb, dcnw, dcnb,
                                    bn2g, bn2b, bn2m, bn2v,
                                    cv2w, bn3g, bn3b, bn3m, bn3v,
                                    apk1, apko, apkd, apk2,
                                    bias1, biaso, bias2, bias3);
    k_cv1<<<800, 256, 0, stream>>>(x, apk1, bias1, y1t);
    k_off<<<800, 256, 0, stream>>>(y1t, apko, biaso, raw);
    k_dcn<<<800, 256, 0, stream>>>(y1t, raw, apkd, bias2, zt);
    k_cv2<<<800, 256, 0, stream>>>(zt, x, apk2, bias3, out);
}

// Round 5
// 245.482 us; speedup vs baseline: 1.0707x; 1.0011x over previous
//
#include <hip/hip_runtime.h>
#include <math.h>

#define HWSZ 6400
#define WIMG 80
#define HIMG 80
#define BEPS 1e-5f

typedef __attribute__((ext_vector_type(8))) short short8;
typedef __attribute__((ext_vector_type(4))) float f32x4;
typedef __attribute__((ext_vector_type(4))) unsigned u32x4;

__device__ __forceinline__ unsigned short f2b(float f) {
    unsigned u = __builtin_bit_cast(unsigned, f);
    u += 0x7fffu + ((u >> 16) & 1u);
    return (unsigned short)(u >> 16);
}
__device__ __forceinline__ float silu_f(float t) { return t / (1.f + __expf(-t)); }

#define BMFMA(a, b, c) __builtin_amdgcn_mfma_f32_16x16x32_bf16(a, b, c, 0, 0, 0)

// ---------------- prep: BN-fold + bf16 A-fragment prepack -------------------
// NEW layouts: apko [36 ks][2 mi][64][8], apkd [36 ks][8 mt][64][8],
// apk2 [4 ks][16 mt][64][8] — contiguous 8/16-wide load groups per k-step.
__global__ __launch_bounds__(256) void k_prep(
    const float* __restrict__ cv1w, const float* __restrict__ g1, const float* __restrict__ b1,
    const float* __restrict__ m1, const float* __restrict__ v1,
    const float* __restrict__ offw, const float* __restrict__ offb,
    const float* __restrict__ dcnw, const float* __restrict__ dcnb,
    const float* __restrict__ g2, const float* __restrict__ b2,
    const float* __restrict__ m2, const float* __restrict__ v2,
    const float* __restrict__ cv2w, const float* __restrict__ g3, const float* __restrict__ b3,
    const float* __restrict__ m3, const float* __restrict__ v3,
    unsigned short* __restrict__ apk1, unsigned short* __restrict__ apko,
    unsigned short* __restrict__ apkd, unsigned short* __restrict__ apk2,
    float* __restrict__ bias1, float* __restrict__ biaso,
    float* __restrict__ bias2, float* __restrict__ bias3)
{
    int idx = blockIdx.x * 256 + threadIdx.x;
    if (idx < 32768) {                       // cv1: [8 mt][8 ks][64][8], K = 256 ch
        int j = idx & 7, L = (idx >> 3) & 63, ks = (idx >> 9) & 7, mt = idx >> 12;
        int o = mt * 16 + (L & 15), k = ks * 32 + (L >> 4) * 8 + j;
        float inv = g1[o] * rsqrtf(v1[o] + BEPS);
        apk1[idx] = f2b(cv1w[o * 256 + k] * inv);
    } else if (idx < 69632) {                // off -> [ks][mi] layout
        int t = idx - 32768;
        int j = t & 7, L = (t >> 3) & 63;
        int mt = t / 18432, rem = t % 18432, ks = rem >> 9;
        int o = mt * 16 + (L & 15);
        int kp = ks * 32 + (L >> 4) * 8 + j;
        int n = kp >> 7, c = kp & 127;
        float wv = (o < 27) ? offw[(size_t)(o * 128 + c) * 9 + n] : 0.f;
        apko[((size_t)(ks * 2 + mt) * 64 + L) * 8 + j] = f2b(wv);
    } else if (idx < 217088) {               // dcn -> [ks][mt] layout, BN2 fold
        int t = idx - 69632;
        int j = t & 7, L = (t >> 3) & 63;
        int mt = t / 18432, rem = t % 18432, ks = rem >> 9;
        int o = mt * 16 + (L & 15);
        int kp = ks * 32 + (L >> 4) * 8 + j;
        int n = kp >> 7, c = kp & 127;
        float inv = g2[o] * rsqrtf(v2[o] + BEPS);
        apkd[((size_t)(ks * 8 + mt) * 64 + L) * 8 + j] = f2b(dcnw[(size_t)(o * 128 + c) * 9 + n] * inv);
    } else if (idx < 249856) {               // cv2 -> [ks][mt] layout, BN3 fold
        int t = idx - 217088;
        int j = t & 7, L = (t >> 3) & 63, ks = (t >> 9) & 3, mt = t >> 11;
        int o = mt * 16 + (L & 15), k = ks * 32 + (L >> 4) * 8 + j;
        float inv = g3[o] * rsqrtf(v3[o] + BEPS);
        apk2[((size_t)(ks * 16 + mt) * 64 + L) * 8 + j] = f2b(cv2w[o * 128 + k] * inv);
    } else if (idx < 250395) {               // biases
        int t = idx - 249856;
        if (t < 128) { float inv = g1[t] * rsqrtf(v1[t] + BEPS); bias1[t] = b1[t] - m1[t] * inv; }
        else if (t < 155) { biaso[t - 128] = offb[t - 128]; }
        else if (t < 283) { int o = t - 155; float inv = g2[o] * rsqrtf(v2[o] + BEPS);
                            bias2[o] = dcnb[o] * inv + b2[o] - m2[o] * inv; }
        else { int o = t - 283; float inv = g3[o] * rsqrtf(v3[o] + BEPS); bias3[o] = b3[o] - m3[o] * inv; }
    }
}

// ---------------- cv1: 1x1 (256->128) + bn1 + silu -> y1t (pixel-major bf16) ----
__global__ __launch_bounds__(256) void k_cv1(
    const float* __restrict__ x, const unsigned short* __restrict__ apk1,
    const float* __restrict__ bias1, unsigned short* __restrict__ y1t)
{
    __shared__ __align__(16) unsigned short sB[20480];   // 8 ks * 4 nt * 16 * 40
    int blk = blockIdx.x;
    int b = blk / 100, pt = blk % 100;
    int p0 = pt * 64;
    int tid = threadIdx.x;
    int lane = tid & 63;
    int w = tid >> 6;
    {
        int px = lane, q = w;
        const float* xb = x + (size_t)b * 256 * HWSZ + p0 + px;
        for (int ks = 0; ks < 8; ++ks) {
            unsigned pk[4];
#pragma unroll
            for (int t = 0; t < 4; ++t) {
                float f0 = xb[(size_t)(ks * 32 + q * 8 + 2 * t) * HWSZ];
                float f1 = xb[(size_t)(ks * 32 + q * 8 + 2 * t + 1) * HWSZ];
                asm("v_cvt_pk_bf16_f32 %0, %1, %2" : "=v"(pk[t]) : "v"(f0), "v"(f1));
            }
            *(u32x4*)&sB[((ks * 4 + (px >> 4)) * 16 + (px & 15)) * 40 + q * 8] =
                (u32x4){pk[0], pk[1], pk[2], pk[3]};
        }
    }
    __syncthreads();
    int n16 = lane & 15, qd = lane >> 4;
    f32x4 acc[2][4];
#pragma unroll
    for (int mi = 0; mi < 2; ++mi)
#pragma unroll
        for (int nt = 0; nt < 4; ++nt) acc[mi][nt] = (f32x4){0.f, 0.f, 0.f, 0.f};
    for (int ks = 0; ks < 8; ++ks) {
        short8 bf[4];
#pragma unroll
        for (int nt = 0; nt < 4; ++nt)
            bf[nt] = *(const short8*)&sB[((ks * 4 + nt) * 16 + n16) * 40 + qd * 8];
        // batch both A-frags before MFMAs (parallel L2 loads)
        short8 a0 = *(const short8*)&apk1[(size_t)(((w * 2 + 0) * 8 + ks) * 64 + lane) * 8];
        short8 a1 = *(const short8*)&apk1[(size_t)(((w * 2 + 1) * 8 + ks) * 64 + lane) * 8];
#pragma unroll
        for (int nt = 0; nt < 4; ++nt) acc[0][nt] = BMFMA(a0, bf[nt], acc[0][nt]);
#pragma unroll
        for (int nt = 0; nt < 4; ++nt) acc[1][nt] = BMFMA(a1, bf[nt], acc[1][nt]);
    }
    __syncthreads();
#pragma unroll
    for (int mi = 0; mi < 2; ++mi)
#pragma unroll
        for (int nt = 0; nt < 4; ++nt)
#pragma unroll
            for (int r = 0; r < 4; ++r) {
                int o = w * 32 + mi * 16 + qd * 4 + r;
                float sv = silu_f(acc[mi][nt][r] + bias1[o]);
                sB[(nt * 16 + n16) * 136 + o] = f2b(sv);
            }
    __syncthreads();
    {
        int px = tid >> 2, qq = tid & 3;
        unsigned short* ytb = y1t + ((size_t)b * HWSZ + p0 + px) * 128;
#pragma unroll
        for (int seg = 0; seg < 4; ++seg) {
            short8 v = *(const short8*)&sB[px * 136 + qq * 32 + seg * 8];
            *(short8*)&ytb[qq * 32 + seg * 8] = v;
        }
    }
}

// ---------------- odc: fused off-conv + DCNv2 + bn2 + silu + cv2 + residual --
// 4x16 pixel tile, +/-2 halo (8x20 rows, XOR-swizzled) staged once. Phases:
// halo stage -> off-conv (raw to LDS, never HBM) -> inline decode + gather +
// MFMA with 8-wide double-buffered A loads -> z epilogue to LDS -> cv2 MFMA
// -> out with residual. 48.1 KB LDS -> 3 blocks/CU.
#define HY2 8
#define HX2 20
#define NH 160

#define ACC8(uu, cb)                                                                   \
    {                                                                                  \
        _Pragma("unroll") for (int t = 0; t < 4; ++t) {                                \
            unsigned uv = (uu)[t];                                                     \
            av[(cb) + 2 * t] = fmaf(wk, __builtin_bit_cast(float, uv << 16),           \
                                    av[(cb) + 2 * t]);                                 \
            av[(cb) + 2 * t + 1] = fmaf(wk, __builtin_bit_cast(float, uv & 0xffff0000u),\
                                        av[(cb) + 2 * t + 1]);                         \
        }                                                                              \
    }

#define LDA8(dst, ksv)                                                                 \
    _Pragma("unroll") for (int mt_ = 0; mt_ < 8; ++mt_)                                \
        dst[mt_] = *(const short8*)&apkd[((size_t)((ksv) * 8 + mt_) * 64 + lane) * 8];

#define MF8(afX, bfv)                                                                  \
    _Pragma("unroll") for (int mt_ = 0; mt_ < 8; ++mt_)                                \
        acc[mt_] = BMFMA(afX[mt_], bfv, acc[mt_]);

#define PACKBF(bfv, sv)                                                                \
    short8 bfv;                                                                        \
    {                                                                                  \
        unsigned pk0, pk1, pk2, pk3;                                                   \
        asm("v_cvt_pk_bf16_f32 %0, %1, %2" : "=v"(pk0) : "v"(av[(sv)*8+0]), "v"(av[(sv)*8+1])); \
        asm("v_cvt_pk_bf16_f32 %0, %1, %2" : "=v"(pk1) : "v"(av[(sv)*8+2]), "v"(av[(sv)*8+3])); \
        asm("v_cvt_pk_bf16_f32 %0, %1, %2" : "=v"(pk2) : "v"(av[(sv)*8+4]), "v"(av[(sv)*8+5])); \
        asm("v_cvt_pk_bf16_f32 %0, %1, %2" : "=v"(pk3) : "v"(av[(sv)*8+6]), "v"(av[(sv)*8+7])); \
        bfv = __builtin_bit_cast(short8, (u32x4){pk0, pk1, pk2, pk3});                 \
    }

__global__ __launch_bounds__(256, 3) void k_odc(
    const unsigned short* __restrict__ y1t,
    const unsigned short* __restrict__ apko, const float* __restrict__ biaso,
    const unsigned short* __restrict__ apkd, const float* __restrict__ bias2,
    const unsigned short* __restrict__ apk2, const float* __restrict__ bias3,
    const float* __restrict__ x, float* __restrict__ out)
{
    __shared__ __align__(16) unsigned short sH[NH * 128];   // 40,960 B halo / z-buffer
    __shared__ float sRaw[27 * 66];                         //  7,128 B off-conv output

    int blk = blockIdx.x;
    int b = blk / 100, pt = blk % 100;
    int h0 = (pt / 5) * 4, w0 = (pt % 5) * 16;
    int tid = threadIdx.x, lane = tid & 63, w = tid >> 6;
    int n16 = lane & 15, qd = lane >> 4;
    int pxl = w * 16 + n16;                 // wave w owns image row h0+w, cols w0..w0+15
    const unsigned short* yb = y1t + (size_t)b * HWSZ * 128;

    // ---- stage halo (8x20 rows, 16B units, XOR-swizzled dest) ----
    for (int i = tid; i < NH * 16; i += 256) {
        int r = i >> 4, u = i & 15;
        int ly = r / HX2, lx = r % HX2;
        int yy = min(max(h0 + ly - 2, 0), HIMG - 1);
        int xx = min(max(w0 + lx - 2, 0), WIMG - 1);
        *(u32x4*)&sH[r * 128 + ((u ^ (r & 7)) * 8)] =
            *(const u32x4*)&yb[(size_t)(yy * WIMG + xx) * 128 + u * 8];
    }
    __syncthreads();

    // ---- off-conv phase: M=32, this wave's 16 px; raw -> LDS ----
    {
        f32x4 oa0 = (f32x4){0.f, 0.f, 0.f, 0.f};
        f32x4 oa1 = (f32x4){0.f, 0.f, 0.f, 0.f};
        for (int n = 0; n < 9; ++n) {
            int dh = n / 3 - 1, dw = n % 3 - 1;
            int hh = h0 + w + dh, ww = w0 + n16 + dw;
            bool valid = ((unsigned)hh < HIMG) && ((unsigned)ww < WIMG);
            int r = (w + 2 + dh) * HX2 + (n16 + 2 + dw);
            int xr = r & 7;
            const unsigned short* hb = &sH[r * 128];
#pragma unroll
            for (int s = 0; s < 4; ++s) {
                short8 bf = *(const short8*)&hb[((s * 4 + qd) ^ xr) * 8];
                if (!valid) bf = (short8){0, 0, 0, 0, 0, 0, 0, 0};
                int ks = n * 4 + s;
                short8 a0 = *(const short8*)&apko[((size_t)(ks * 2 + 0) * 64 + lane) * 8];
                short8 a1 = *(const short8*)&apko[((size_t)(ks * 2 + 1) * 64 + lane) * 8];
                oa0 = BMFMA(a0, bf, oa0);
                oa1 = BMFMA(a1, bf, oa1);
            }
        }
#pragma unroll
        for (int mi = 0; mi < 2; ++mi)
#pragma unroll
            for (int r4 = 0; r4 < 4; ++r4) {
                int o = mi * 16 + qd * 4 + r4;
                if (o < 27) {
                    float t = (mi ? oa1[r4] : oa0[r4]) + biaso[o];
                    if (o >= 18) t = 1.f / (1.f + __expf(-t));
                    sRaw[o * 66 + pxl] = t;
                }
            }
    }
    __syncthreads();

    // ---- dcn phase: inline decode + LDS gather + double-buffered A stream ----
    f32x4 acc[8];
#pragma unroll
    for (int mt = 0; mt < 8; ++mt) acc[mt] = (f32x4){0.f, 0.f, 0.f, 0.f};
    int hI = h0 + w, wI = w0 + n16;

    for (int n = 0; n < 9; ++n) {
        float dy = sRaw[(2 * n) * 66 + pxl];
        float dx = sRaw[(2 * n + 1) * 66 + pxl];
        float mk = sRaw[(18 + n) * 66 + pxl];
        float py = (float)(hI - 1 + n / 3) + dy;
        float px = (float)(wI - 1 + n % 3) + dx;
        float y0f = floorf(py), x0f = floorf(px);
        float fy = py - y0f, fxv = px - x0f;
        int y0 = (int)y0f, x0 = (int)x0f;
        float wy0 = (1.f - fy) * mk, wy1 = fy * mk, fx1 = 1.f - fxv;

        int ks0 = n * 4;
        short8 afA[8], afB[8];
        LDA8(afA, ks0)                       // 8 loads in flight under the gather

        float av[32];
#pragma unroll
        for (int j = 0; j < 32; ++j) av[j] = 0.f;
#pragma unroll
        for (int k = 0; k < 4; ++k) {
            int yy = y0 + (k >> 1), xx = x0 + (k & 1);
            bool vld = ((unsigned)yy < HIMG) && ((unsigned)xx < WIMG);
            float wk = ((k >> 1) ? wy1 : wy0) * ((k & 1) ? fxv : fx1);
            if (!vld) wk = 0.f;
            int yc = min(max(yy, 0), HIMG - 1);
            int xc = min(max(xx, 0), WIMG - 1);
            int ly = yc - h0 + 2, lx = xc - w0 + 2;
            if (((unsigned)ly < HY2) && ((unsigned)lx < HX2)) {
                int r = ly * HX2 + lx;
                const unsigned short* hb = &sH[r * 128];
                int xr = r & 7;
                u32x4 u0 = *(const u32x4*)&hb[((0 + qd) ^ xr) * 8];
                u32x4 u1 = *(const u32x4*)&hb[((4 + qd) ^ xr) * 8];
                u32x4 u2 = *(const u32x4*)&hb[((8 + qd) ^ xr) * 8];
                u32x4 u3 = *(const u32x4*)&hb[((12 + qd) ^ xr) * 8];
                ACC8(u0, 0) ACC8(u1, 8) ACC8(u2, 16) ACC8(u3, 24)
            } else if (wk != 0.f) {          // rare: offset beyond halo
                const unsigned short* src = &yb[(size_t)(yc * WIMG + xc) * 128 + qd * 8];
                u32x4 u0 = *(const u32x4*)src;
                u32x4 u1 = *(const u32x4*)(src + 32);
                u32x4 u2 = *(const u32x4*)(src + 64);
                u32x4 u3 = *(const u32x4*)(src + 96);
                ACC8(u0, 0) ACC8(u1, 8) ACC8(u2, 16) ACC8(u3, 24)
            }
        }
        LDA8(afB, ks0 + 1)
        { PACKBF(bf0, 0) MF8(afA, bf0) }
        LDA8(afA, ks0 + 2)
        { PACKBF(bf1, 1) MF8(afB, bf1) }
        LDA8(afB, ks0 + 3)
        { PACKBF(bf2, 2) MF8(afA, bf2) }
        { PACKBF(bf3, 3) MF8(afB, bf3) }
    }
    __syncthreads();                         // all waves done with sH/sRaw

    // ---- z epilogue: bn2 + silu -> pixel-major bf16 in LDS (reuse sH) ----
    unsigned short* sE = sH;
#pragma unroll
    for (int mt = 0; mt < 8; ++mt)
#pragma unroll
        for (int r4 = 0; r4 < 4; ++r4) {
            int o = mt * 16 + qd * 4 + r4;
            float sv = silu_f(acc[mt][r4] + bias2[o]);
            sE[pxl * 136 + o] = f2b(sv);
        }
    __syncthreads();

    // ---- cv2 phase: 1x1 (128->256), M=256 per wave over its 16 px ----
    f32x4 c2[16];
#pragma unroll
    for (int mt = 0; mt < 16; ++mt) c2[mt] = (f32x4){0.f, 0.f, 0.f, 0.f};
#pragma unroll
    for (int ks = 0; ks < 4; ++ks) {
        short8 bf = *(const short8*)&sE[pxl * 136 + ks * 32 + qd * 8];
        short8 cfA[8], cfB[8];
#pragma unroll
        for (int mt_ = 0; mt_ < 8; ++mt_)
            cfA[mt_] = *(const short8*)&apk2[((size_t)(ks * 16 + mt_) * 64 + lane) * 8];
#pragma unroll
        for (int mt_ = 0; mt_ < 8; ++mt_)
            cfB[mt_] = *(const short8*)&apk2[((size_t)(ks * 16 + 8 + mt_) * 64 + lane) * 8];
#pragma unroll
        for (int mt_ = 0; mt_ < 8; ++mt_) c2[mt_] = BMFMA(cfA[mt_], bf, c2[mt_]);
#pragma unroll
        for (int mt_ = 0; mt_ < 8; ++mt_) c2[8 + mt_] = BMFMA(cfB[mt_], bf, c2[8 + mt_]);
    }
    int p = (h0 + w) * WIMG + w0 + n16;
    const float* xb = x + (size_t)b * 256 * HWSZ;
    float* ob = out + (size_t)b * 256 * HWSZ;
#pragma unroll
    for (int mt = 0; mt < 16; ++mt)
#pragma unroll
        for (int r4 = 0; r4 < 4; ++r4) {
            int o = mt * 16 + qd * 4 + r4;
            size_t idx = (size_t)o * HWSZ + p;
            ob[idx] = xb[idx] + silu_f(c2[mt][r4] + bias3[o]);
        }
}

extern "C" void kernel_launch(void* const* d_in, const int* in_sizes, int n_in,
                              void* d_out, int out_size, void* d_ws, size_t ws_size,
                              hipStream_t stream) {
    const float* x     = (const float*)d_in[0];
    const float* cv1w  = (const float*)d_in[1];
    const float* bn1g  = (const float*)d_in[2];
    const float* bn1b  = (const float*)d_in[3];
    const float* bn1m  = (const float*)d_in[4];
    const float* bn1v  = (const float*)d_in[5];
    const float* offw  = (const float*)d_in[6];
    const float* offb  = (const float*)d_in[7];
    const float* dcnw  = (const float*)d_in[8];
    const float* dcnb  = (const float*)d_in[9];
    const float* bn2g  = (const float*)d_in[10];
    const float* bn2b  = (const float*)d_in[11];
    const float* bn2m  = (const float*)d_in[12];
    const float* bn2v  = (const float*)d_in[13];
    const float* cv2w  = (const float*)d_in[14];
    const float* bn3g  = (const float*)d_in[15];
    const float* bn3b  = (const float*)d_in[16];
    const float* bn3m  = (const float*)d_in[17];
    const float* bn3v  = (const float*)d_in[18];
    float* out = (float*)d_out;

    // workspace layout (float units)
    float* base = (float*)d_ws;
    unsigned short* y1t = (unsigned short*)base;                 // 8*6400*128 bf16
    unsigned short* apk1 = (unsigned short*)(base + 7936000);
    unsigned short* apko = (unsigned short*)(base + 7952384);
    unsigned short* apkd = (unsigned short*)(base + 7970816);
    unsigned short* apk2 = (unsigned short*)(base + 8044544);
    float* bias1 = base + 8060928;
    float* biaso = base + 8061056;
    float* bias2 = base + 8061088;
    float* bias3 = base + 8061216;

    k_prep<<<979, 256, 0, stream>>>(cv1w, bn1g, bn1b, bn1m, bn1v,
                                    offw, offb, dcnw, dcnb,
                                    bn2g, bn2b, bn2m, bn2v,
                                    cv2w, bn3g, bn3b, bn3m, bn3v,
                                    apk1, apko, apkd, apk2,
                                    bias1, biaso, bias2, bias3);
    k_cv1<<<800, 256, 0, stream>>>(x, apk1, bias1, y1t);
    k_odc<<<800, 256, 0, stream>>>(y1t, apko, biaso, apkd, bias2,
                                   apk2, bias3, x, out);
}

// Round 6
// 235.119 us; speedup vs baseline: 1.1179x; 1.0441x over previous
//
#include <hip/hip_runtime.h>
#include <math.h>

#define HWSZ 6400
#define WIMG 80
#define HIMG 80
#define BEPS 1e-5f

typedef __attribute__((ext_vector_type(8))) short short8;
typedef __attribute__((ext_vector_type(4))) float f32x4;
typedef __attribute__((ext_vector_type(4))) unsigned u32x4;

__device__ __forceinline__ unsigned short f2b(float f) {
    unsigned u = __builtin_bit_cast(unsigned, f);
    u += 0x7fffu + ((u >> 16) & 1u);
    return (unsigned short)(u >> 16);
}
__device__ __forceinline__ float silu_f(float t) { return t / (1.f + __expf(-t)); }

#define BMFMA(a, b, c) __builtin_amdgcn_mfma_f32_16x16x32_bf16(a, b, c, 0, 0, 0)

// async global->LDS DMA, 16B per lane; LDS dest = wave-uniform base + lane*16
__device__ __forceinline__ void gload16(const unsigned short* g, unsigned short* l) {
    __builtin_amdgcn_global_load_lds(
        (const __attribute__((address_space(1))) unsigned int*)g,
        (__attribute__((address_space(3))) unsigned int*)l, 16, 0, 0);
}

// ---------------- prep: BN-fold + bf16 A-fragment prepack -------------------
// apko [36 ks][2 mi][64][8], apkd [36 ks][8 mt][64][8], apk2 [4 ks][16 mt][64][8]
__global__ __launch_bounds__(256) void k_prep(
    const float* __restrict__ cv1w, const float* __restrict__ g1, const float* __restrict__ b1,
    const float* __restrict__ m1, const float* __restrict__ v1,
    const float* __restrict__ offw, const float* __restrict__ offb,
    const float* __restrict__ dcnw, const float* __restrict__ dcnb,
    const float* __restrict__ g2, const float* __restrict__ b2,
    const float* __restrict__ m2, const float* __restrict__ v2,
    const float* __restrict__ cv2w, const float* __restrict__ g3, const float* __restrict__ b3,
    const float* __restrict__ m3, const float* __restrict__ v3,
    unsigned short* __restrict__ apk1, unsigned short* __restrict__ apko,
    unsigned short* __restrict__ apkd, unsigned short* __restrict__ apk2,
    float* __restrict__ bias1, float* __restrict__ biaso,
    float* __restrict__ bias2, float* __restrict__ bias3)
{
    int idx = blockIdx.x * 256 + threadIdx.x;
    if (idx < 32768) {                       // cv1: [8 mt][8 ks][64][8], K = 256 ch
        int j = idx & 7, L = (idx >> 3) & 63, ks = (idx >> 9) & 7, mt = idx >> 12;
        int o = mt * 16 + (L & 15), k = ks * 32 + (L >> 4) * 8 + j;
        float inv = g1[o] * rsqrtf(v1[o] + BEPS);
        apk1[idx] = f2b(cv1w[o * 256 + k] * inv);
    } else if (idx < 69632) {                // off -> [ks][mi]
        int t = idx - 32768;
        int j = t & 7, L = (t >> 3) & 63;
        int mt = t / 18432, rem = t % 18432, ks = rem >> 9;
        int o = mt * 16 + (L & 15);
        int kp = ks * 32 + (L >> 4) * 8 + j;
        int n = kp >> 7, c = kp & 127;
        float wv = (o < 27) ? offw[(size_t)(o * 128 + c) * 9 + n] : 0.f;
        apko[((size_t)(ks * 2 + mt) * 64 + L) * 8 + j] = f2b(wv);
    } else if (idx < 217088) {               // dcn -> [ks][mt], BN2 fold
        int t = idx - 69632;
        int j = t & 7, L = (t >> 3) & 63;
        int mt = t / 18432, rem = t % 18432, ks = rem >> 9;
        int o = mt * 16 + (L & 15);
        int kp = ks * 32 + (L >> 4) * 8 + j;
        int n = kp >> 7, c = kp & 127;
        float inv = g2[o] * rsqrtf(v2[o] + BEPS);
        apkd[((size_t)(ks * 8 + mt) * 64 + L) * 8 + j] = f2b(dcnw[(size_t)(o * 128 + c) * 9 + n] * inv);
    } else if (idx < 249856) {               // cv2 -> [ks][mt], BN3 fold
        int t = idx - 217088;
        int j = t & 7, L = (t >> 3) & 63, ks = (t >> 9) & 3, mt = t >> 11;
        int o = mt * 16 + (L & 15), k = ks * 32 + (L >> 4) * 8 + j;
        float inv = g3[o] * rsqrtf(v3[o] + BEPS);
        apk2[((size_t)(ks * 16 + mt) * 64 + L) * 8 + j] = f2b(cv2w[o * 128 + k] * inv);
    } else if (idx < 250395) {               // biases
        int t = idx - 249856;
        if (t < 128) { float inv = g1[t] * rsqrtf(v1[t] + BEPS); bias1[t] = b1[t] - m1[t] * inv; }
        else if (t < 155) { biaso[t - 128] = offb[t - 128]; }
        else if (t < 283) { int o = t - 155; float inv = g2[o] * rsqrtf(v2[o] + BEPS);
                            bias2[o] = dcnb[o] * inv + b2[o] - m2[o] * inv; }
        else { int o = t - 283; float inv = g3[o] * rsqrtf(v3[o] + BEPS); bias3[o] = b3[o] - m3[o] * inv; }
    }
}

// ---------------- cv1: 1x1 (256->128) + bn1 + silu -> y1t (pixel-major bf16) ----
__global__ __launch_bounds__(256) void k_cv1(
    const float* __restrict__ x, const unsigned short* __restrict__ apk1,
    const float* __restrict__ bias1, unsigned short* __restrict__ y1t)
{
    __shared__ __align__(16) unsigned short sB[20480];
    int blk = blockIdx.x;
    int b = blk / 100, pt = blk % 100;
    int p0 = pt * 64;
    int tid = threadIdx.x;
    int lane = tid & 63;
    int w = tid >> 6;
    {
        int px = lane, q = w;
        const float* xb = x + (size_t)b * 256 * HWSZ + p0 + px;
        for (int ks = 0; ks < 8; ++ks) {
            unsigned pk[4];
#pragma unroll
            for (int t = 0; t < 4; ++t) {
                float f0 = xb[(size_t)(ks * 32 + q * 8 + 2 * t) * HWSZ];
                float f1 = xb[(size_t)(ks * 32 + q * 8 + 2 * t + 1) * HWSZ];
                asm("v_cvt_pk_bf16_f32 %0, %1, %2" : "=v"(pk[t]) : "v"(f0), "v"(f1));
            }
            *(u32x4*)&sB[((ks * 4 + (px >> 4)) * 16 + (px & 15)) * 40 + q * 8] =
                (u32x4){pk[0], pk[1], pk[2], pk[3]};
        }
    }
    __syncthreads();
    int n16 = lane & 15, qd = lane >> 4;
    f32x4 acc[2][4];
#pragma unroll
    for (int mi = 0; mi < 2; ++mi)
#pragma unroll
        for (int nt = 0; nt < 4; ++nt) acc[mi][nt] = (f32x4){0.f, 0.f, 0.f, 0.f};
    for (int ks = 0; ks < 8; ++ks) {
        short8 bf[4];
#pragma unroll
        for (int nt = 0; nt < 4; ++nt)
            bf[nt] = *(const short8*)&sB[((ks * 4 + nt) * 16 + n16) * 40 + qd * 8];
        short8 a0 = *(const short8*)&apk1[(size_t)(((w * 2 + 0) * 8 + ks) * 64 + lane) * 8];
        short8 a1 = *(const short8*)&apk1[(size_t)(((w * 2 + 1) * 8 + ks) * 64 + lane) * 8];
#pragma unroll
        for (int nt = 0; nt < 4; ++nt) acc[0][nt] = BMFMA(a0, bf[nt], acc[0][nt]);
#pragma unroll
        for (int nt = 0; nt < 4; ++nt) acc[1][nt] = BMFMA(a1, bf[nt], acc[1][nt]);
    }
    __syncthreads();
#pragma unroll
    for (int mi = 0; mi < 2; ++mi)
#pragma unroll
        for (int nt = 0; nt < 4; ++nt)
#pragma unroll
            for (int r = 0; r < 4; ++r) {
                int o = w * 32 + mi * 16 + qd * 4 + r;
                float sv = silu_f(acc[mi][nt][r] + bias1[o]);
                sB[(nt * 16 + n16) * 136 + o] = f2b(sv);
            }
    __syncthreads();
    {
        int px = tid >> 2, qq = tid & 3;
        unsigned short* ytb = y1t + ((size_t)b * HWSZ + p0 + px) * 128;
#pragma unroll
        for (int seg = 0; seg < 4; ++seg) {
            short8 v = *(const short8*)&sB[px * 136 + qq * 32 + seg * 8];
            *(short8*)&ytb[qq * 32 + seg * 8] = v;
        }
    }
}

// ---------------- odc: fused off + DCNv2 + bn2 + silu + cv2 + residual -------
// All weight fragments stream through a 16 KB LDS ping-pong via
// global_load_lds (53 x 8 KB slabs: off 9, dcn 36, cv2 8). One barrier per
// slab; DMA overlaps consume; A-operand latency off the MFMA chain.
#define HY2 8
#define HX2 20
#define NH 160
#define NSLAB 53

#define ACC8(uu, cb)                                                                   \
    {                                                                                  \
        _Pragma("unroll") for (int t = 0; t < 4; ++t) {                                \
            unsigned uv = (uu)[t];                                                     \
            av[(cb) + 2 * t] = fmaf(wk, __builtin_bit_cast(float, uv << 16),           \
                                    av[(cb) + 2 * t]);                                 \
            av[(cb) + 2 * t + 1] = fmaf(wk, __builtin_bit_cast(float, uv & 0xffff0000u),\
                                        av[(cb) + 2 * t + 1]);                         \
        }                                                                              \
    }

__device__ __forceinline__ const unsigned short* slab_src(
    const unsigned short* apko, const unsigned short* apkd,
    const unsigned short* apk2, int i) {
    if (i < 9)  return apko + (size_t)i * 4096;
    if (i < 45) return apkd + (size_t)(i - 9) * 4096;
    return apk2 + (size_t)(i - 45) * 4096;
}

#define STAGE(i, bp)                                                                   \
    {                                                                                  \
        const unsigned short* src_ = slab_src(apko, apkd, apk2, (i));                  \
        gload16(src_ + ((w * 2 + 0) * 512 + lane * 8), &sAf[bp][(w * 2 + 0) * 512]);   \
        gload16(src_ + ((w * 2 + 1) * 512 + lane * 8), &sAf[bp][(w * 2 + 1) * 512]);   \
    }

__global__ __launch_bounds__(256, 2) void k_odc(
    const unsigned short* __restrict__ y1t,
    const unsigned short* __restrict__ apko, const float* __restrict__ biaso,
    const unsigned short* __restrict__ apkd, const float* __restrict__ bias2,
    const unsigned short* __restrict__ apk2, const float* __restrict__ bias3,
    const float* __restrict__ x, float* __restrict__ out)
{
    __shared__ __align__(16) unsigned short sH[NH * 128];    // 40,960 B halo / z-buf
    __shared__ float sRaw[27 * 66];                          //  7,128 B
    __shared__ __align__(16) unsigned short sAf[2][4096];    // 16,384 B af ping-pong

    int blk = blockIdx.x;
    int b = blk / 100, pt = blk % 100;
    int h0 = (pt / 5) * 4, w0 = (pt % 5) * 16;
    int tid = threadIdx.x, lane = tid & 63, w = tid >> 6;
    int n16 = lane & 15, qd = lane >> 4;
    int pxl = w * 16 + n16;
    const unsigned short* yb = y1t + (size_t)b * HWSZ * 128;

    // ---- stage halo (8x20 rows, XOR-swizzled dest) + first af slab ----
    for (int i = tid; i < NH * 16; i += 256) {
        int r = i >> 4, u = i & 15;
        int ly = r / HX2, lx = r % HX2;
        int yy = min(max(h0 + ly - 2, 0), HIMG - 1);
        int xx = min(max(w0 + lx - 2, 0), WIMG - 1);
        *(u32x4*)&sH[r * 128 + ((u ^ (r & 7)) * 8)] =
            *(const u32x4*)&yb[(size_t)(yy * WIMG + xx) * 128 + u * 8];
    }
    STAGE(0, 0)
    __syncthreads();                          // halo + slab0 ready
    int bufp = 0;

    // ---- off phase: slabs 0..8 (one per tap); raw -> LDS ----
    {
        f32x4 oa0 = (f32x4){0.f, 0.f, 0.f, 0.f};
        f32x4 oa1 = (f32x4){0.f, 0.f, 0.f, 0.f};
        for (int n = 0; n < 9; ++n) {
            STAGE(n + 1, bufp ^ 1)
            int dh = n / 3 - 1, dw = n % 3 - 1;
            int hh = h0 + w + dh, ww = w0 + n16 + dw;
            bool valid = ((unsigned)hh < HIMG) && ((unsigned)ww < WIMG);
            int r = (w + 2 + dh) * HX2 + (n16 + 2 + dw);
            int xr = r & 7;
            const unsigned short* hb = &sH[r * 128];
#pragma unroll
            for (int s = 0; s < 4; ++s) {
                short8 bf = *(const short8*)&hb[((s * 4 + qd) ^ xr) * 8];
                if (!valid) bf = (short8){0, 0, 0, 0, 0, 0, 0, 0};
                short8 a0 = *(const short8*)&sAf[bufp][(s * 2 + 0) * 512 + lane * 8];
                short8 a1 = *(const short8*)&sAf[bufp][(s * 2 + 1) * 512 + lane * 8];
                oa0 = BMFMA(a0, bf, oa0);
                oa1 = BMFMA(a1, bf, oa1);
            }
            if (n == 8) {
#pragma unroll
                for (int mi = 0; mi < 2; ++mi)
#pragma unroll
                    for (int r4 = 0; r4 < 4; ++r4) {
                        int o = mi * 16 + qd * 4 + r4;
                        if (o < 27) {
                            float t = (mi ? oa1[r4] : oa0[r4]) + biaso[o];
                            if (o >= 18) t = 1.f / (1.f + __expf(-t));
                            sRaw[o * 66 + pxl] = t;
                        }
                    }
            }
            __syncthreads();
            bufp ^= 1;
        }
    }

    // ---- dcn phase: slabs 9..44 (one per k-step) ----
    f32x4 acc[8];
#pragma unroll
    for (int mt = 0; mt < 8; ++mt) acc[mt] = (f32x4){0.f, 0.f, 0.f, 0.f};
    int hI = h0 + w, wI = w0 + n16;

    for (int n = 0; n < 9; ++n) {
        float av[32];
#pragma unroll
        for (int s = 0; s < 4; ++s) {
            int slab = 9 + n * 4 + s;
            if (slab + 1 < NSLAB) STAGE(slab + 1, bufp ^ 1)
            if (s == 0) {
                float dy = sRaw[(2 * n) * 66 + pxl];
                float dx = sRaw[(2 * n + 1) * 66 + pxl];
                float mk = sRaw[(18 + n) * 66 + pxl];
                float py = (float)(hI - 1 + n / 3) + dy;
                float px = (float)(wI - 1 + n % 3) + dx;
                float y0f = floorf(py), x0f = floorf(px);
                float fy = py - y0f, fxv = px - x0f;
                int y0 = (int)y0f, x0 = (int)x0f;
                float wy0 = (1.f - fy) * mk, wy1 = fy * mk, fx1 = 1.f - fxv;
#pragma unroll
                for (int j = 0; j < 32; ++j) av[j] = 0.f;
#pragma unroll
                for (int k = 0; k < 4; ++k) {
                    int yy = y0 + (k >> 1), xx = x0 + (k & 1);
                    bool vld = ((unsigned)yy < HIMG) && ((unsigned)xx < WIMG);
                    float wk = ((k >> 1) ? wy1 : wy0) * ((k & 1) ? fxv : fx1);
                    if (!vld) wk = 0.f;
                    int yc = min(max(yy, 0), HIMG - 1);
                    int xc = min(max(xx, 0), WIMG - 1);
                    int ly = yc - h0 + 2, lx = xc - w0 + 2;
                    if (((unsigned)ly < HY2) && ((unsigned)lx < HX2)) {
                        int r = ly * HX2 + lx;
                        const unsigned short* hb = &sH[r * 128];
                        int xr = r & 7;
                        u32x4 u0 = *(const u32x4*)&hb[((0 + qd) ^ xr) * 8];
                        u32x4 u1 = *(const u32x4*)&hb[((4 + qd) ^ xr) * 8];
                        u32x4 u2 = *(const u32x4*)&hb[((8 + qd) ^ xr) * 8];
                        u32x4 u3 = *(const u32x4*)&hb[((12 + qd) ^ xr) * 8];
                        ACC8(u0, 0) ACC8(u1, 8) ACC8(u2, 16) ACC8(u3, 24)
                    } else if (wk != 0.f) {
                        const unsigned short* src = &yb[(size_t)(yc * WIMG + xc) * 128 + qd * 8];
                        u32x4 u0 = *(const u32x4*)src;
                        u32x4 u1 = *(const u32x4*)(src + 32);
                        u32x4 u2 = *(const u32x4*)(src + 64);
                        u32x4 u3 = *(const u32x4*)(src + 96);
                        ACC8(u0, 0) ACC8(u1, 8) ACC8(u2, 16) ACC8(u3, 24)
                    }
                }
            }
            // pack this k-step's B-frag, 8 ds_read af + 8 MFMA
            unsigned pk0, pk1, pk2, pk3;
            asm("v_cvt_pk_bf16_f32 %0, %1, %2" : "=v"(pk0) : "v"(av[s * 8 + 0]), "v"(av[s * 8 + 1]));
            asm("v_cvt_pk_bf16_f32 %0, %1, %2" : "=v"(pk1) : "v"(av[s * 8 + 2]), "v"(av[s * 8 + 3]));
            asm("v_cvt_pk_bf16_f32 %0, %1, %2" : "=v"(pk2) : "v"(av[s * 8 + 4]), "v"(av[s * 8 + 5]));
            asm("v_cvt_pk_bf16_f32 %0, %1, %2" : "=v"(pk3) : "v"(av[s * 8 + 6]), "v"(av[s * 8 + 7]));
            short8 bfv = __builtin_bit_cast(short8, (u32x4){pk0, pk1, pk2, pk3});
#pragma unroll
            for (int mt = 0; mt < 8; ++mt) {
                short8 af = *(const short8*)&sAf[bufp][mt * 512 + lane * 8];
                acc[mt] = BMFMA(af, bfv, acc[mt]);
            }
            if (n == 8 && s == 3) {
                // z epilogue: bn2 + silu -> pixel-major bf16 (reuse sH)
                unsigned short* sE = sH;
#pragma unroll
                for (int mt = 0; mt < 8; ++mt)
#pragma unroll
                    for (int r4 = 0; r4 < 4; ++r4) {
                        int o = mt * 16 + qd * 4 + r4;
                        float sv = silu_f(acc[mt][r4] + bias2[o]);
                        sE[pxl * 136 + o] = f2b(sv);
                    }
            }
            __syncthreads();
            bufp ^= 1;
        }
    }

    // ---- cv2 phase: slabs 45..52 (half-ks each: 8 mt rows) ----
    const unsigned short* sE = sH;
    f32x4 c2[16];
#pragma unroll
    for (int mt = 0; mt < 16; ++mt) c2[mt] = (f32x4){0.f, 0.f, 0.f, 0.f};
#pragma unroll
    for (int h2 = 0; h2 < 8; ++h2) {
        int slab = 45 + h2;
        if (slab + 1 < NSLAB) STAGE(slab + 1, bufp ^ 1)
        int ks = h2 >> 1, half = h2 & 1;
        short8 bf = *(const short8*)&sE[pxl * 136 + ks * 32 + qd * 8];
#pragma unroll
        for (int mt = 0; mt < 8; ++mt) {
            short8 af = *(const short8*)&sAf[bufp][mt * 512 + lane * 8];
            c2[half * 8 + mt] = BMFMA(af, bf, c2[half * 8 + mt]);
        }
        __syncthreads();
        bufp ^= 1;
    }
    int p = (h0 + w) * WIMG + w0 + n16;
    const float* xb = x + (size_t)b * 256 * HWSZ;
    float* ob = out + (size_t)b * 256 * HWSZ;
#pragma unroll
    for (int mt = 0; mt < 16; ++mt)
#pragma unroll
        for (int r4 = 0; r4 < 4; ++r4) {
            int o = mt * 16 + qd * 4 + r4;
            size_t idx = (size_t)o * HWSZ + p;
            ob[idx] = xb[idx] + silu_f(c2[mt][r4] + bias3[o]);
        }
}

extern "C" void kernel_launch(void* const* d_in, const int* in_sizes, int n_in,
                              void* d_out, int out_size, void* d_ws, size_t ws_size,
                              hipStream_t stream) {
    const float* x     = (const float*)d_in[0];
    const float* cv1w  = (const float*)d_in[1];
    const float* bn1g  = (const float*)d_in[2];
    const float* bn1b  = (const float*)d_in[3];
    const float* bn1m  = (const float*)d_in[4];
    const float* bn1v  = (const float*)d_in[5];
    const float* offw  = (const float*)d_in[6];
    const float* offb  = (const float*)d_in[7];
    const float* dcnw  = (const float*)d_in[8];
    const float* dcnb  = (const float*)d_in[9];
    const float* bn2g  = (const float*)d_in[10];
    const float* bn2b  = (const float*)d_in[11];
    const float* bn2m  = (const float*)d_in[12];
    const float* bn2v  = (const float*)d_in[13];
    const float* cv2w  = (const float*)d_in[14];
    const float* bn3g  = (const float*)d_in[15];
    const float* bn3b  = (const float*)d_in[16];
    const float* bn3m  = (const float*)d_in[17];
    const float* bn3v  = (const float*)d_in[18];
    float* out = (float*)d_out;

    // workspace layout (float units)
    float* base = (float*)d_ws;
    unsigned short* y1t = (unsigned short*)base;                 // 8*6400*128 bf16
    unsigned short* apk1 = (unsigned short*)(base + 7936000);
    unsigned short* apko = (unsigned short*)(base + 7952384);
    unsigned short* apkd = (unsigned short*)(base + 7970816);
    unsigned short* apk2 = (unsigned short*)(base + 8044544);
    float* bias1 = base + 8060928;
    float* biaso = base + 8061056;
    float* bias2 = base + 8061088;
    float* bias3 = base + 8061216;

    k_prep<<<979, 256, 0, stream>>>(cv1w, bn1g, bn1b, bn1m, bn1v,
                                    offw, offb, dcnw, dcnb,
                                    bn2g, bn2b, bn2m, bn2v,
                                    cv2w, bn3g, bn3b, bn3m, bn3v,
                                    apk1, apko, apkd, apk2,
                                    bias1, biaso, bias2, bias3);
    k_cv1<<<800, 256, 0, stream>>>(x, apk1, bias1, y1t);
    k_odc<<<800, 256, 0, stream>>>(y1t, apko, biaso, apkd, bias2,
                                   apk2, bias3, x, out);
}